// Round 1
// baseline (11770.679 us; speedup 1.0000x reference)
//
#include <hip/hip_runtime.h>

#define NN 100000
#define NE 1600000
#define FIN 64
#define HID 128
#define NL 4
#define NG 512
#define FFN 300
#define BN_EPS 1e-5f

static inline size_t alignup(size_t x) { return (x + 255) & ~(size_t)255; }

// ---- degree / normalization ----
__global__ void k_deg_init(float* deg) {
    int i = blockIdx.x * 256 + threadIdx.x;
    if (i < NN) deg[i] = 1.0f;  // self-loop
}

__global__ void k_deg_edges(const int* __restrict__ col, float* __restrict__ deg) {
    int e = blockIdx.x * 256 + threadIdx.x;
    if (e < NE) atomicAdd(&deg[col[e]], 1.0f);
}

__global__ void k_dinv(float* deg) {
    int i = blockIdx.x * 256 + threadIdx.x;
    if (i < NN) deg[i] = rsqrtf(deg[i]);  // deg >= 1 always (self-loops)
}

// ---- encoder: h[N,128] = x[N,64] @ W[64,128] + b ; 64 rows/block, 256 thr ----
__global__ __launch_bounds__(256) void k_enc(const float* __restrict__ x,
                                             const float* __restrict__ W,
                                             const float* __restrict__ b,
                                             float* __restrict__ h) {
    __shared__ float sW[FIN * HID];        // 32 KB
    __shared__ float sx[64 * (FIN + 1)];   // padded stride 65 -> no bank conflict
    int t = threadIdx.x;
    int row0 = blockIdx.x * 64;
    for (int i = t; i < FIN * HID; i += 256) sW[i] = W[i];
    for (int i = t; i < 64 * FIN; i += 256) {
        int r = i >> 6, k = i & 63;
        sx[r * (FIN + 1) + k] = (row0 + r < NN) ? x[(size_t)(row0 + r) * FIN + k] : 0.0f;
    }
    __syncthreads();
    int tx = t & 15, ty = t >> 4;
    int j0 = tx * 8, r0 = ty * 4;
    float acc[4][8];
    #pragma unroll
    for (int r = 0; r < 4; ++r) {
        #pragma unroll
        for (int j = 0; j < 8; ++j) acc[r][j] = 0.0f;
    }
    for (int k = 0; k < FIN; ++k) {
        float xv[4];
        #pragma unroll
        for (int r = 0; r < 4; ++r) xv[r] = sx[(r0 + r) * (FIN + 1) + k];
        float4 w0 = *(const float4*)&sW[k * HID + j0];
        float4 w1 = *(const float4*)&sW[k * HID + j0 + 4];
        float wv[8] = {w0.x, w0.y, w0.z, w0.w, w1.x, w1.y, w1.z, w1.w};
        #pragma unroll
        for (int r = 0; r < 4; ++r) {
            #pragma unroll
            for (int j = 0; j < 8; ++j) acc[r][j] += xv[r] * wv[j];
        }
    }
    #pragma unroll
    for (int r = 0; r < 4; ++r) {
        int row = row0 + r0 + r;
        if (row < NN) {
            float4 o0, o1;
            o0.x = acc[r][0] + b[j0 + 0]; o0.y = acc[r][1] + b[j0 + 1];
            o0.z = acc[r][2] + b[j0 + 2]; o0.w = acc[r][3] + b[j0 + 3];
            o1.x = acc[r][4] + b[j0 + 4]; o1.y = acc[r][5] + b[j0 + 5];
            o1.z = acc[r][6] + b[j0 + 6]; o1.w = acc[r][7] + b[j0 + 7];
            *(float4*)&h[(size_t)row * HID + j0] = o0;
            *(float4*)&h[(size_t)row * HID + j0 + 4] = o1;
        }
    }
}

// ---- layer GEMM: hw[N,128] = h[N,128] @ W[128,128] ; 64 rows/block, 256 thr ----
__global__ __launch_bounds__(256) void k_gemm128(const float* __restrict__ h,
                                                 const float* __restrict__ W,
                                                 float* __restrict__ hw) {
    __shared__ float sW[64 * HID];         // 32 KB, K-chunk of 64
    __shared__ float sx[64 * (HID + 1)];   // 33 KB, padded stride 129
    int t = threadIdx.x;
    int row0 = blockIdx.x * 64;
    for (int i = t; i < 64 * HID; i += 256) {
        int r = i >> 7, k = i & 127;
        sx[r * (HID + 1) + k] = (row0 + r < NN) ? h[(size_t)(row0 + r) * HID + k] : 0.0f;
    }
    int tx = t & 15, ty = t >> 4;
    int j0 = tx * 8, r0 = ty * 4;
    float acc[4][8];
    #pragma unroll
    for (int r = 0; r < 4; ++r) {
        #pragma unroll
        for (int j = 0; j < 8; ++j) acc[r][j] = 0.0f;
    }
    for (int kk = 0; kk < HID; kk += 64) {
        __syncthreads();   // sx ready (first iter) / previous sW consumed
        for (int i = t; i < 64 * HID; i += 256) sW[i] = W[kk * HID + i];
        __syncthreads();
        for (int k = 0; k < 64; ++k) {
            float xv[4];
            #pragma unroll
            for (int r = 0; r < 4; ++r) xv[r] = sx[(r0 + r) * (HID + 1) + kk + k];
            float4 w0 = *(const float4*)&sW[k * HID + j0];
            float4 w1 = *(const float4*)&sW[k * HID + j0 + 4];
            float wv[8] = {w0.x, w0.y, w0.z, w0.w, w1.x, w1.y, w1.z, w1.w};
            #pragma unroll
            for (int r = 0; r < 4; ++r) {
                #pragma unroll
                for (int j = 0; j < 8; ++j) acc[r][j] += xv[r] * wv[j];
            }
        }
    }
    #pragma unroll
    for (int r = 0; r < 4; ++r) {
        int row = row0 + r0 + r;
        if (row < NN) {
            float4 o0, o1;
            o0.x = acc[r][0]; o0.y = acc[r][1]; o0.z = acc[r][2]; o0.w = acc[r][3];
            o1.x = acc[r][4]; o1.y = acc[r][5]; o1.z = acc[r][6]; o1.w = acc[r][7];
            *(float4*)&hw[(size_t)row * HID + j0] = o0;
            *(float4*)&hw[(size_t)row * HID + j0 + 4] = o1;
        }
    }
}

// ---- edge scatter: hnew[c] += dinv[r]*dinv[c] * hw[r] ; 32 thr/edge, float4 ----
__global__ void k_scatter(const int* __restrict__ src, const int* __restrict__ dst,
                          const float* __restrict__ dinv, const float* __restrict__ hw,
                          float* __restrict__ hnew) {
    int idx = blockIdx.x * 256 + threadIdx.x;
    int e = idx >> 5;
    if (e >= NE) return;
    int d = (idx & 31) * 4;
    int r = src[e], c = dst[e];
    float nrm = dinv[r] * dinv[c];
    float4 v = *(const float4*)(hw + (size_t)r * HID + d);
    float* p = hnew + (size_t)c * HID + d;
    atomicAdd(p + 0, nrm * v.x);
    atomicAdd(p + 1, nrm * v.y);
    atomicAdd(p + 2, nrm * v.z);
    atomicAdd(p + 3, nrm * v.w);
}

// ---- self-loop + bias + BN + ReLU + residual (in-place on hagg) ----
__global__ void k_post(float* __restrict__ hagg, const float* __restrict__ hw,
                       const float* __restrict__ hprev, const float* __restrict__ dinv,
                       const float* __restrict__ bias, const float* __restrict__ gamma,
                       const float* __restrict__ beta, const float* __restrict__ mean,
                       const float* __restrict__ var, int with_res) {
    int idx = blockIdx.x * 256 + threadIdx.x;
    int i = idx >> 5;
    if (i >= NN) return;
    int d0 = (idx & 31) * 4;
    size_t base = (size_t)i * HID + d0;
    float di = dinv[i];
    float selfw = di * di;
    float4 agg = *(const float4*)(hagg + base);
    float4 w = *(const float4*)(hw + base);
    float av[4] = {agg.x, agg.y, agg.z, agg.w};
    float wv[4] = {w.x, w.y, w.z, w.w};
    float out[4];
    #pragma unroll
    for (int c = 0; c < 4; ++c) {
        int d = d0 + c;
        float v = av[c] + selfw * wv[c] + bias[d];
        v = (v - mean[d]) * rsqrtf(var[d] + BN_EPS) * gamma[d] + beta[d];
        out[c] = fmaxf(v, 0.0f);
    }
    if (with_res) {
        float4 p = *(const float4*)(hprev + base);
        out[0] += p.x; out[1] += p.y; out[2] += p.z; out[3] += p.w;
    }
    float4 o;
    o.x = out[0]; o.y = out[1]; o.z = out[2]; o.w = out[3];
    *(float4*)(hagg + base) = o;
}

// ---- global mean pool (sums + counts via atomics) ----
__global__ void k_pool(const float* __restrict__ h, const int* __restrict__ batch,
                       float* __restrict__ gsum, float* __restrict__ gcnt) {
    int idx = blockIdx.x * 256 + threadIdx.x;
    int i = idx >> 5;
    if (i >= NN) return;
    int d = (idx & 31) * 4;
    int g = batch[i];
    float4 v = *(const float4*)(h + (size_t)i * HID + d);
    float* p = gsum + (size_t)g * HID + d;
    atomicAdd(p + 0, v.x);
    atomicAdd(p + 1, v.y);
    atomicAdd(p + 2, v.z);
    atomicAdd(p + 3, v.w);
    if ((idx & 31) == 0) atomicAdd(gcnt + g, 1.0f);
}

// ---- MLP ----
__global__ void k_mlp0(const float* __restrict__ gsum, const float* __restrict__ gcnt,
                       const float* __restrict__ W, const float* __restrict__ b,
                       float* __restrict__ out) {
    __shared__ float srow[HID];
    int g = blockIdx.x, t = threadIdx.x;  // 128 threads
    float rcp = 1.0f / fmaxf(gcnt[g], 1.0f);
    if (t < HID) srow[t] = gsum[(size_t)g * HID + t] * rcp;
    __syncthreads();
    for (int j = t; j < FFN; j += 128) {
        float acc = b[j];
        for (int k = 0; k < HID; ++k) acc += srow[k] * W[k * FFN + j];
        out[(size_t)g * FFN + j] = fmaxf(acc, 0.0f);
    }
}

__global__ void k_mlp1(const float* __restrict__ in, const float* __restrict__ W,
                       const float* __restrict__ b, float* __restrict__ out) {
    __shared__ float srow[FFN];
    int g = blockIdx.x, t = threadIdx.x;  // 128 threads
    for (int k = t; k < FFN; k += 128) srow[k] = in[(size_t)g * FFN + k];
    __syncthreads();
    for (int j = t; j < FFN; j += 128) {
        float acc = b[j];
        for (int k = 0; k < FFN; ++k) acc += srow[k] * W[k * FFN + j];
        out[(size_t)g * FFN + j] = fmaxf(acc, 0.0f);
    }
}

__global__ void k_mlp2(const float* __restrict__ in, const float* __restrict__ W,
                       const float* __restrict__ b, float* __restrict__ out) {
    int g = blockIdx.x, lane = threadIdx.x;  // 64 threads = 1 wave
    float acc = 0.0f;
    for (int k = lane; k < FFN; k += 64) acc += in[(size_t)g * FFN + k] * W[k];
    for (int off = 32; off > 0; off >>= 1) acc += __shfl_down(acc, off);
    if (lane == 0) out[g] = acc + b[0];
}

extern "C" void kernel_launch(void* const* d_in, const int* in_sizes, int n_in,
                              void* d_out, int out_size, void* d_ws, size_t ws_size,
                              hipStream_t stream) {
    const float* x    = (const float*)d_in[0];
    const int*   ei   = (const int*)d_in[1];    // [2,E]: rows then cols
    const int*   batch= (const int*)d_in[2];
    const float* encW = (const float*)d_in[3];
    const float* encb = (const float*)d_in[4];
    const float* Ws   = (const float*)d_in[5];
    const float* bs   = (const float*)d_in[6];
    const float* gam  = (const float*)d_in[7];
    const float* bet  = (const float*)d_in[8];
    const float* mean = (const float*)d_in[9];
    const float* var  = (const float*)d_in[10];
    const float* W0   = (const float*)d_in[11];
    const float* b0   = (const float*)d_in[12];
    const float* W1   = (const float*)d_in[13];
    const float* b1   = (const float*)d_in[14];
    const float* W2   = (const float*)d_in[15];
    const float* b2   = (const float*)d_in[16];
    float* out = (float*)d_out;

    char* w = (char*)d_ws;
    float* dinv = (float*)w; w += alignup((size_t)NN * 4);
    float* hA   = (float*)w; w += alignup((size_t)NN * HID * 4);
    float* hB   = (float*)w; w += alignup((size_t)NN * HID * 4);
    float* hw_  = (float*)w; w += alignup((size_t)NN * HID * 4);
    float* gsum = (float*)w; w += alignup((size_t)NG * HID * 4);
    float* gcnt = (float*)w; w += alignup((size_t)NG * 4);
    float* m0   = (float*)w; w += alignup((size_t)NG * FFN * 4);
    float* m1   = (float*)w; w += alignup((size_t)NG * FFN * 4);

    // degrees -> dinv
    k_deg_init<<<(NN + 255) / 256, 256, 0, stream>>>(dinv);
    k_deg_edges<<<(NE + 255) / 256, 256, 0, stream>>>(ei + NE, dinv);
    k_dinv<<<(NN + 255) / 256, 256, 0, stream>>>(dinv);

    // encoder
    k_enc<<<(NN + 63) / 64, 256, 0, stream>>>(x, encW, encb, hA);

    float* hcur = hA;
    float* hnext = hB;
    for (int l = 0; l < NL; ++l) {
        k_gemm128<<<(NN + 63) / 64, 256, 0, stream>>>(hcur, Ws + (size_t)l * HID * HID, hw_);
        hipMemsetAsync(hnext, 0, (size_t)NN * HID * 4, stream);
        k_scatter<<<(NE * 32) / 256, 256, 0, stream>>>(ei, ei + NE, dinv, hw_, hnext);
        k_post<<<(NN * 32 + 255) / 256, 256, 0, stream>>>(hnext, hw_, hcur, dinv,
            bs + l * HID, gam + l * HID, bet + l * HID, mean + l * HID, var + l * HID,
            l > 0 ? 1 : 0);
        float* tmp = hcur; hcur = hnext; hnext = tmp;
    }

    // pool + MLP
    hipMemsetAsync(gsum, 0, (size_t)NG * HID * 4, stream);
    hipMemsetAsync(gcnt, 0, (size_t)NG * 4, stream);
    k_pool<<<(NN * 32 + 255) / 256, 256, 0, stream>>>(hcur, batch, gsum, gcnt);
    k_mlp0<<<NG, 128, 0, stream>>>(gsum, gcnt, W0, b0, m0);
    k_mlp1<<<NG, 128, 0, stream>>>(m0, W1, b1, m1);
    k_mlp2<<<NG, 64, 0, stream>>>(m1, W2, b2, out);
}

// Round 2
// 1510.496 us; speedup vs baseline: 7.7926x; 7.7926x over previous
//
#include <hip/hip_runtime.h>

#define NN 100000
#define NE 1600000
#define FIN 64
#define HID 128
#define NL 4
#define NG 512
#define FFN 300
#define BN_EPS 1e-5f
#define SCAN_BLK 1024
#define NSCAN ((NN + SCAN_BLK - 1) / SCAN_BLK)   // 98

static inline size_t alignup(size_t x) { return (x + 255) & ~(size_t)255; }

// ======================= CSR build =======================
__global__ void k_count_init(int* counts) {
    int i = blockIdx.x * 256 + threadIdx.x;
    if (i < NN) counts[i] = 0;
}

__global__ void k_count(const int* __restrict__ col, int* __restrict__ counts) {
    int e = blockIdx.x * 256 + threadIdx.x;
    if (e < NE) atomicAdd(&counts[col[e]], 1);
}

__global__ void k_dinv(const int* __restrict__ counts, float* __restrict__ dinv) {
    int i = blockIdx.x * 256 + threadIdx.x;
    if (i < NN) dinv[i] = rsqrtf((float)(counts[i] + 1));  // +1 self-loop
}

__global__ __launch_bounds__(256) void k_scan1(const int* __restrict__ counts,
                                               int* __restrict__ incl,
                                               int* __restrict__ bsums) {
    __shared__ int s[256];
    int t = threadIdx.x;
    int base = blockIdx.x * SCAN_BLK + t * 4;
    int c[4];
    #pragma unroll
    for (int j = 0; j < 4; ++j) c[j] = (base + j < NN) ? counts[base + j] : 0;
    int tsum = c[0] + c[1] + c[2] + c[3];
    s[t] = tsum;
    __syncthreads();
    for (int off = 1; off < 256; off <<= 1) {
        int v = (t >= off) ? s[t - off] : 0;
        __syncthreads();
        s[t] += v;
        __syncthreads();
    }
    if (t == 255) bsums[blockIdx.x] = s[255];
    int run = s[t] - tsum;  // exclusive across threads
    #pragma unroll
    for (int j = 0; j < 4; ++j) {
        run += c[j];
        if (base + j < NN) incl[base + j] = run;  // inclusive within block
    }
}

__global__ void k_scan2(int* bsums) {  // single block, 128 threads
    __shared__ int s[128];
    int t = threadIdx.x;
    int v = (t < NSCAN) ? bsums[t] : 0;
    s[t] = v;
    __syncthreads();
    for (int off = 1; off < 128; off <<= 1) {
        int u = (t >= off) ? s[t - off] : 0;
        __syncthreads();
        s[t] += u;
        __syncthreads();
    }
    if (t < NSCAN) bsums[t] = s[t] - v;  // exclusive block offsets
}

__global__ void k_scan3(const int* __restrict__ counts, const int* __restrict__ incl,
                        const int* __restrict__ bsums, int* __restrict__ offs,
                        int* __restrict__ cursor) {
    int i = blockIdx.x * 256 + threadIdx.x;
    if (i >= NN) return;
    int off = incl[i] - counts[i] + bsums[i / SCAN_BLK];
    offs[i] = off;
    cursor[i] = off;
}

__global__ void k_fill(const int* __restrict__ row, const int* __restrict__ col,
                       const float* __restrict__ dinv, int* __restrict__ cursor,
                       int* __restrict__ csr_src, float* __restrict__ csr_w) {
    int e = blockIdx.x * 256 + threadIdx.x;
    if (e >= NE) return;
    int r = row[e], c = col[e];
    int pos = atomicAdd(&cursor[c], 1);
    csr_src[pos] = r;
    csr_w[pos] = dinv[r] * dinv[c];
}

// ======================= encoder =======================
__global__ __launch_bounds__(256) void k_enc(const float* __restrict__ x,
                                             const float* __restrict__ W,
                                             const float* __restrict__ b,
                                             float* __restrict__ h) {
    __shared__ float sW[FIN * HID];
    __shared__ float sx[64 * (FIN + 1)];
    int t = threadIdx.x;
    int row0 = blockIdx.x * 64;
    for (int i = t; i < FIN * HID; i += 256) sW[i] = W[i];
    for (int i = t; i < 64 * FIN; i += 256) {
        int r = i >> 6, k = i & 63;
        sx[r * (FIN + 1) + k] = (row0 + r < NN) ? x[(size_t)(row0 + r) * FIN + k] : 0.0f;
    }
    __syncthreads();
    int tx = t & 15, ty = t >> 4;
    int j0 = tx * 8, r0 = ty * 4;
    float acc[4][8];
    #pragma unroll
    for (int r = 0; r < 4; ++r)
        #pragma unroll
        for (int j = 0; j < 8; ++j) acc[r][j] = 0.0f;
    for (int k = 0; k < FIN; ++k) {
        float xv[4];
        #pragma unroll
        for (int r = 0; r < 4; ++r) xv[r] = sx[(r0 + r) * (FIN + 1) + k];
        float4 w0 = *(const float4*)&sW[k * HID + j0];
        float4 w1 = *(const float4*)&sW[k * HID + j0 + 4];
        float wv[8] = {w0.x, w0.y, w0.z, w0.w, w1.x, w1.y, w1.z, w1.w};
        #pragma unroll
        for (int r = 0; r < 4; ++r)
            #pragma unroll
            for (int j = 0; j < 8; ++j) acc[r][j] += xv[r] * wv[j];
    }
    #pragma unroll
    for (int r = 0; r < 4; ++r) {
        int rowi = row0 + r0 + r;
        if (rowi < NN) {
            float4 o0, o1;
            o0.x = acc[r][0] + b[j0 + 0]; o0.y = acc[r][1] + b[j0 + 1];
            o0.z = acc[r][2] + b[j0 + 2]; o0.w = acc[r][3] + b[j0 + 3];
            o1.x = acc[r][4] + b[j0 + 4]; o1.y = acc[r][5] + b[j0 + 5];
            o1.z = acc[r][6] + b[j0 + 6]; o1.w = acc[r][7] + b[j0 + 7];
            *(float4*)&h[(size_t)rowi * HID + j0] = o0;
            *(float4*)&h[(size_t)rowi * HID + j0 + 4] = o1;
        }
    }
}

// ======================= layer GEMM =======================
__global__ __launch_bounds__(256) void k_gemm128(const float* __restrict__ h,
                                                 const float* __restrict__ W,
                                                 float* __restrict__ hw) {
    __shared__ float sW[64 * HID];
    __shared__ float sx[64 * (HID + 1)];
    int t = threadIdx.x;
    int row0 = blockIdx.x * 64;
    for (int i = t; i < 64 * HID; i += 256) {
        int r = i >> 7, k = i & 127;
        sx[r * (HID + 1) + k] = (row0 + r < NN) ? h[(size_t)(row0 + r) * HID + k] : 0.0f;
    }
    int tx = t & 15, ty = t >> 4;
    int j0 = tx * 8, r0 = ty * 4;
    float acc[4][8];
    #pragma unroll
    for (int r = 0; r < 4; ++r)
        #pragma unroll
        for (int j = 0; j < 8; ++j) acc[r][j] = 0.0f;
    for (int kk = 0; kk < HID; kk += 64) {
        __syncthreads();
        for (int i = t; i < 64 * HID; i += 256) sW[i] = W[kk * HID + i];
        __syncthreads();
        for (int k = 0; k < 64; ++k) {
            float xv[4];
            #pragma unroll
            for (int r = 0; r < 4; ++r) xv[r] = sx[(r0 + r) * (HID + 1) + kk + k];
            float4 w0 = *(const float4*)&sW[k * HID + j0];
            float4 w1 = *(const float4*)&sW[k * HID + j0 + 4];
            float wv[8] = {w0.x, w0.y, w0.z, w0.w, w1.x, w1.y, w1.z, w1.w};
            #pragma unroll
            for (int r = 0; r < 4; ++r)
                #pragma unroll
                for (int j = 0; j < 8; ++j) acc[r][j] += xv[r] * wv[j];
        }
    }
    #pragma unroll
    for (int r = 0; r < 4; ++r) {
        int rowi = row0 + r0 + r;
        if (rowi < NN) {
            float4 o0, o1;
            o0.x = acc[r][0]; o0.y = acc[r][1]; o0.z = acc[r][2]; o0.w = acc[r][3];
            o1.x = acc[r][4]; o1.y = acc[r][5]; o1.z = acc[r][6]; o1.w = acc[r][7];
            *(float4*)&hw[(size_t)rowi * HID + j0] = o0;
            *(float4*)&hw[(size_t)rowi * HID + j0 + 4] = o1;
        }
    }
}

// ======= fused gather + self-loop + bias + BN + ReLU + residual =======
// one wave (64 lanes) per node; lane handles 2 features (float2)
__global__ __launch_bounds__(256) void k_gather(
    const int* __restrict__ offs, const int* __restrict__ ends,
    const int* __restrict__ csr_src, const float* __restrict__ csr_w,
    const float* __restrict__ dinv,
    const float* __restrict__ hw, const float* __restrict__ hprev,
    const float* __restrict__ bias, const float* __restrict__ gamma,
    const float* __restrict__ beta, const float* __restrict__ mean,
    const float* __restrict__ var,
    float* __restrict__ hout, int with_res) {
    int node = (blockIdx.x * 256 + threadIdx.x) >> 6;
    if (node >= NN) return;
    int lane = threadIdx.x & 63;
    int d0 = lane * 2;
    int s = offs[node], e = ends[node];
    float a0 = 0.0f, a1 = 0.0f;
    int j = s;
    for (; j + 1 < e; j += 2) {  // 2-deep for load overlap
        int s0 = csr_src[j], s1 = csr_src[j + 1];
        float w0 = csr_w[j], w1 = csr_w[j + 1];
        float2 v0 = *(const float2*)(hw + (size_t)s0 * HID + d0);
        float2 v1 = *(const float2*)(hw + (size_t)s1 * HID + d0);
        a0 += w0 * v0.x + w1 * v1.x;
        a1 += w0 * v0.y + w1 * v1.y;
    }
    if (j < e) {
        int s0 = csr_src[j];
        float w0 = csr_w[j];
        float2 v0 = *(const float2*)(hw + (size_t)s0 * HID + d0);
        a0 += w0 * v0.x;
        a1 += w0 * v0.y;
    }
    float di = dinv[node];
    float sw = di * di;
    float2 hv = *(const float2*)(hw + (size_t)node * HID + d0);
    a0 += sw * hv.x;
    a1 += sw * hv.y;
    // bias + BN + ReLU (+ residual)
    float o0 = a0 + bias[d0 + 0];
    float o1 = a1 + bias[d0 + 1];
    o0 = (o0 - mean[d0 + 0]) * rsqrtf(var[d0 + 0] + BN_EPS) * gamma[d0 + 0] + beta[d0 + 0];
    o1 = (o1 - mean[d0 + 1]) * rsqrtf(var[d0 + 1] + BN_EPS) * gamma[d0 + 1] + beta[d0 + 1];
    o0 = fmaxf(o0, 0.0f);
    o1 = fmaxf(o1, 0.0f);
    if (with_res) {
        float2 p = *(const float2*)(hprev + (size_t)node * HID + d0);
        o0 += p.x;
        o1 += p.y;
    }
    float2 o;
    o.x = o0; o.y = o1;
    *(float2*)(hout + (size_t)node * HID + d0) = o;
}

// ======================= pool + MLP =======================
__global__ void k_pool(const float* __restrict__ h, const int* __restrict__ batch,
                       float* __restrict__ gsum, float* __restrict__ gcnt) {
    int idx = blockIdx.x * 256 + threadIdx.x;
    int i = idx >> 5;
    if (i >= NN) return;
    int d = (idx & 31) * 4;
    int g = batch[i];
    float4 v = *(const float4*)(h + (size_t)i * HID + d);
    float* p = gsum + (size_t)g * HID + d;
    atomicAdd(p + 0, v.x);
    atomicAdd(p + 1, v.y);
    atomicAdd(p + 2, v.z);
    atomicAdd(p + 3, v.w);
    if ((idx & 31) == 0) atomicAdd(gcnt + g, 1.0f);
}

__global__ void k_mlp0(const float* __restrict__ gsum, const float* __restrict__ gcnt,
                       const float* __restrict__ W, const float* __restrict__ b,
                       float* __restrict__ out) {
    __shared__ float srow[HID];
    int g = blockIdx.x, t = threadIdx.x;  // 128 threads
    float rcp = 1.0f / fmaxf(gcnt[g], 1.0f);
    if (t < HID) srow[t] = gsum[(size_t)g * HID + t] * rcp;
    __syncthreads();
    for (int j = t; j < FFN; j += 128) {
        float acc = b[j];
        for (int k = 0; k < HID; ++k) acc += srow[k] * W[k * FFN + j];
        out[(size_t)g * FFN + j] = fmaxf(acc, 0.0f);
    }
}

__global__ void k_mlp1(const float* __restrict__ in, const float* __restrict__ W,
                       const float* __restrict__ b, float* __restrict__ out) {
    __shared__ float srow[FFN];
    int g = blockIdx.x, t = threadIdx.x;  // 128 threads
    for (int k = t; k < FFN; k += 128) srow[k] = in[(size_t)g * FFN + k];
    __syncthreads();
    for (int j = t; j < FFN; j += 128) {
        float acc = b[j];
        for (int k = 0; k < FFN; ++k) acc += srow[k] * W[k * FFN + j];
        out[(size_t)g * FFN + j] = fmaxf(acc, 0.0f);
    }
}

__global__ void k_mlp2(const float* __restrict__ in, const float* __restrict__ W,
                       const float* __restrict__ b, float* __restrict__ out) {
    int g = blockIdx.x, lane = threadIdx.x;  // 64 threads
    float acc = 0.0f;
    for (int k = lane; k < FFN; k += 64) acc += in[(size_t)g * FFN + k] * W[k];
    for (int off = 32; off > 0; off >>= 1) acc += __shfl_down(acc, off);
    if (lane == 0) out[g] = acc + b[0];
}

extern "C" void kernel_launch(void* const* d_in, const int* in_sizes, int n_in,
                              void* d_out, int out_size, void* d_ws, size_t ws_size,
                              hipStream_t stream) {
    const float* x    = (const float*)d_in[0];
    const int*   ei   = (const int*)d_in[1];    // [2,E]: rows then cols
    const int*   batch= (const int*)d_in[2];
    const float* encW = (const float*)d_in[3];
    const float* encb = (const float*)d_in[4];
    const float* Ws   = (const float*)d_in[5];
    const float* bs   = (const float*)d_in[6];
    const float* gam  = (const float*)d_in[7];
    const float* bet  = (const float*)d_in[8];
    const float* mean = (const float*)d_in[9];
    const float* var  = (const float*)d_in[10];
    const float* W0   = (const float*)d_in[11];
    const float* b0   = (const float*)d_in[12];
    const float* W1   = (const float*)d_in[13];
    const float* b1   = (const float*)d_in[14];
    const float* W2   = (const float*)d_in[15];
    const float* b2   = (const float*)d_in[16];
    float* out = (float*)d_out;

    char* w = (char*)d_ws;
    float* dinv    = (float*)w; w += alignup((size_t)NN * 4);
    int*   counts  = (int*)w;   w += alignup((size_t)NN * 4);
    int*   incl    = (int*)w;   w += alignup((size_t)NN * 4);
    int*   bsums   = (int*)w;   w += alignup((size_t)NSCAN * 4);
    int*   offs    = (int*)w;   w += alignup((size_t)NN * 4);
    int*   cursor  = (int*)w;   w += alignup((size_t)NN * 4);
    int*   csr_src = (int*)w;   w += alignup((size_t)NE * 4);
    float* csr_w   = (float*)w; w += alignup((size_t)NE * 4);
    float* hA      = (float*)w; w += alignup((size_t)NN * HID * 4);
    float* hB      = (float*)w; w += alignup((size_t)NN * HID * 4);
    float* hw_     = (float*)w; w += alignup((size_t)NN * HID * 4);
    float* gsum    = (float*)w; w += alignup((size_t)NG * HID * 4);
    float* gcnt    = (float*)w; w += alignup((size_t)NG * 4);
    float* m0      = (float*)w; w += alignup((size_t)NG * FFN * 4);
    float* m1      = (float*)w; w += alignup((size_t)NG * FFN * 4);

    const int* row = ei;
    const int* col = ei + NE;

    // ---- CSR build (per launch; deterministic work) ----
    k_count_init<<<(NN + 255) / 256, 256, 0, stream>>>(counts);
    k_count<<<(NE + 255) / 256, 256, 0, stream>>>(col, counts);
    k_dinv<<<(NN + 255) / 256, 256, 0, stream>>>(counts, dinv);
    k_scan1<<<NSCAN, 256, 0, stream>>>(counts, incl, bsums);
    k_scan2<<<1, 128, 0, stream>>>(bsums);
    k_scan3<<<(NN + 255) / 256, 256, 0, stream>>>(counts, incl, bsums, offs, cursor);
    k_fill<<<(NE + 255) / 256, 256, 0, stream>>>(row, col, dinv, cursor, csr_src, csr_w);

    // ---- encoder ----
    k_enc<<<(NN + 63) / 64, 256, 0, stream>>>(x, encW, encb, hA);

    float* hcur = hA;
    float* hnext = hB;
    for (int l = 0; l < NL; ++l) {
        k_gemm128<<<(NN + 63) / 64, 256, 0, stream>>>(hcur, Ws + (size_t)l * HID * HID, hw_);
        k_gather<<<(NN * 64 + 255) / 256, 256, 0, stream>>>(
            offs, cursor, csr_src, csr_w, dinv, hw_, hcur,
            bs + l * HID, gam + l * HID, bet + l * HID, mean + l * HID, var + l * HID,
            hnext, l > 0 ? 1 : 0);
        float* tmp = hcur; hcur = hnext; hnext = tmp;
    }

    // ---- pool + MLP ----
    hipMemsetAsync(gsum, 0, (size_t)NG * HID * 4, stream);
    hipMemsetAsync(gcnt, 0, (size_t)NG * 4, stream);
    k_pool<<<(NN * 32 + 255) / 256, 256, 0, stream>>>(hcur, batch, gsum, gcnt);
    k_mlp0<<<NG, 128, 0, stream>>>(gsum, gcnt, W0, b0, m0);
    k_mlp1<<<NG, 128, 0, stream>>>(m0, W1, b1, m1);
    k_mlp2<<<NG, 64, 0, stream>>>(m1, W2, b2, out);
}

// Round 3
// 1176.740 us; speedup vs baseline: 10.0028x; 1.2836x over previous
//
#include <hip/hip_runtime.h>

#define NN 100000
#define NE 1600000
#define FIN 64
#define HID 128
#define NL 4
#define NG 512
#define FFN 300
#define BN_EPS 1e-5f
#define SCAN_BLK 1024
#define NSCAN ((NN + SCAN_BLK - 1) / SCAN_BLK)   // 98

static inline size_t alignup(size_t x) { return (x + 255) & ~(size_t)255; }

// ======================= CSR build =======================
__global__ void k_count_init(int* counts) {
    int i = blockIdx.x * 256 + threadIdx.x;
    if (i < NN) counts[i] = 0;
}

__global__ void k_count(const int* __restrict__ col, int* __restrict__ counts) {
    int e = blockIdx.x * 256 + threadIdx.x;
    if (e < NE) atomicAdd(&counts[col[e]], 1);
}

__global__ void k_dinv(const int* __restrict__ counts, float* __restrict__ dinv) {
    int i = blockIdx.x * 256 + threadIdx.x;
    if (i < NN) dinv[i] = rsqrtf((float)(counts[i] + 1));  // +1 self-loop
}

__global__ __launch_bounds__(256) void k_scan1(const int* __restrict__ counts,
                                               int* __restrict__ incl,
                                               int* __restrict__ bsums) {
    __shared__ int s[256];
    int t = threadIdx.x;
    int base = blockIdx.x * SCAN_BLK + t * 4;
    int c[4];
    #pragma unroll
    for (int j = 0; j < 4; ++j) c[j] = (base + j < NN) ? counts[base + j] : 0;
    int tsum = c[0] + c[1] + c[2] + c[3];
    s[t] = tsum;
    __syncthreads();
    for (int off = 1; off < 256; off <<= 1) {
        int v = (t >= off) ? s[t - off] : 0;
        __syncthreads();
        s[t] += v;
        __syncthreads();
    }
    if (t == 255) bsums[blockIdx.x] = s[255];
    int run = s[t] - tsum;  // exclusive across threads
    #pragma unroll
    for (int j = 0; j < 4; ++j) {
        run += c[j];
        if (base + j < NN) incl[base + j] = run;  // inclusive within block
    }
}

__global__ void k_scan2(int* bsums) {  // single block, 128 threads
    __shared__ int s[128];
    int t = threadIdx.x;
    int v = (t < NSCAN) ? bsums[t] : 0;
    s[t] = v;
    __syncthreads();
    for (int off = 1; off < 128; off <<= 1) {
        int u = (t >= off) ? s[t - off] : 0;
        __syncthreads();
        s[t] += u;
        __syncthreads();
    }
    if (t < NSCAN) bsums[t] = s[t] - v;  // exclusive block offsets
}

__global__ void k_scan3(const int* __restrict__ counts, const int* __restrict__ incl,
                        const int* __restrict__ bsums, int* __restrict__ offs,
                        int* __restrict__ cursor) {
    int i = blockIdx.x * 256 + threadIdx.x;
    if (i >= NN) return;
    int off = incl[i] - counts[i] + bsums[i / SCAN_BLK];
    offs[i] = off;
    cursor[i] = off;
}

__global__ void k_fill(const int* __restrict__ row, const int* __restrict__ col,
                       const float* __restrict__ dinv, int* __restrict__ cursor,
                       int* __restrict__ csr_src, float* __restrict__ csr_w) {
    int e = blockIdx.x * 256 + threadIdx.x;
    if (e >= NE) return;
    int r = row[e], c = col[e];
    int pos = atomicAdd(&cursor[c], 1);
    csr_src[pos] = r;
    csr_w[pos] = dinv[r] * dinv[c];
}

// ======================= encoder =======================
__global__ __launch_bounds__(256) void k_enc(const float* __restrict__ x,
                                             const float* __restrict__ W,
                                             const float* __restrict__ b,
                                             float* __restrict__ h) {
    __shared__ float sW[FIN * HID];
    __shared__ float sx[64 * (FIN + 1)];
    int t = threadIdx.x;
    int row0 = blockIdx.x * 64;
    for (int i = t; i < FIN * HID; i += 256) sW[i] = W[i];
    for (int i = t; i < 64 * FIN; i += 256) {
        int r = i >> 6, k = i & 63;
        sx[r * (FIN + 1) + k] = (row0 + r < NN) ? x[(size_t)(row0 + r) * FIN + k] : 0.0f;
    }
    __syncthreads();
    int tx = t & 15, ty = t >> 4;
    int j0 = tx * 8, r0 = ty * 4;
    float acc[4][8];
    #pragma unroll
    for (int r = 0; r < 4; ++r)
        #pragma unroll
        for (int j = 0; j < 8; ++j) acc[r][j] = 0.0f;
    for (int k = 0; k < FIN; ++k) {
        float xv[4];
        #pragma unroll
        for (int r = 0; r < 4; ++r) xv[r] = sx[(r0 + r) * (FIN + 1) + k];
        float4 w0 = *(const float4*)&sW[k * HID + j0];
        float4 w1 = *(const float4*)&sW[k * HID + j0 + 4];
        float wv[8] = {w0.x, w0.y, w0.z, w0.w, w1.x, w1.y, w1.z, w1.w};
        #pragma unroll
        for (int r = 0; r < 4; ++r)
            #pragma unroll
            for (int j = 0; j < 8; ++j) acc[r][j] += xv[r] * wv[j];
    }
    #pragma unroll
    for (int r = 0; r < 4; ++r) {
        int rowi = row0 + r0 + r;
        if (rowi < NN) {
            float4 o0, o1;
            o0.x = acc[r][0] + b[j0 + 0]; o0.y = acc[r][1] + b[j0 + 1];
            o0.z = acc[r][2] + b[j0 + 2]; o0.w = acc[r][3] + b[j0 + 3];
            o1.x = acc[r][4] + b[j0 + 4]; o1.y = acc[r][5] + b[j0 + 5];
            o1.z = acc[r][6] + b[j0 + 6]; o1.w = acc[r][7] + b[j0 + 7];
            *(float4*)&h[(size_t)rowi * HID + j0] = o0;
            *(float4*)&h[(size_t)rowi * HID + j0 + 4] = o1;
        }
    }
}

// ======================= layer GEMM =======================
__global__ __launch_bounds__(256) void k_gemm128(const float* __restrict__ h,
                                                 const float* __restrict__ W,
                                                 float* __restrict__ hw) {
    __shared__ float sW[64 * HID];
    __shared__ float sx[64 * (HID + 1)];
    int t = threadIdx.x;
    int row0 = blockIdx.x * 64;
    for (int i = t; i < 64 * HID; i += 256) {
        int r = i >> 7, k = i & 127;
        sx[r * (HID + 1) + k] = (row0 + r < NN) ? h[(size_t)(row0 + r) * HID + k] : 0.0f;
    }
    int tx = t & 15, ty = t >> 4;
    int j0 = tx * 8, r0 = ty * 4;
    float acc[4][8];
    #pragma unroll
    for (int r = 0; r < 4; ++r)
        #pragma unroll
        for (int j = 0; j < 8; ++j) acc[r][j] = 0.0f;
    for (int kk = 0; kk < HID; kk += 64) {
        __syncthreads();
        for (int i = t; i < 64 * HID; i += 256) sW[i] = W[kk * HID + i];
        __syncthreads();
        for (int k = 0; k < 64; ++k) {
            float xv[4];
            #pragma unroll
            for (int r = 0; r < 4; ++r) xv[r] = sx[(r0 + r) * (HID + 1) + kk + k];
            float4 w0 = *(const float4*)&sW[k * HID + j0];
            float4 w1 = *(const float4*)&sW[k * HID + j0 + 4];
            float wv[8] = {w0.x, w0.y, w0.z, w0.w, w1.x, w1.y, w1.z, w1.w};
            #pragma unroll
            for (int r = 0; r < 4; ++r)
                #pragma unroll
                for (int j = 0; j < 8; ++j) acc[r][j] += xv[r] * wv[j];
        }
    }
    #pragma unroll
    for (int r = 0; r < 4; ++r) {
        int rowi = row0 + r0 + r;
        if (rowi < NN) {
            float4 o0, o1;
            o0.x = acc[r][0]; o0.y = acc[r][1]; o0.z = acc[r][2]; o0.w = acc[r][3];
            o1.x = acc[r][4]; o1.y = acc[r][5]; o1.z = acc[r][6]; o1.w = acc[r][7];
            *(float4*)&hw[(size_t)rowi * HID + j0] = o0;
            *(float4*)&hw[(size_t)rowi * HID + j0 + 4] = o1;
        }
    }
}

// ======= fused gather + self-loop + bias + BN + ReLU + residual =======
// one wave (64 lanes) per node; lane handles 2 features (float2)
__global__ __launch_bounds__(256) void k_gather(
    const int* __restrict__ offs, const int* __restrict__ ends,
    const int* __restrict__ csr_src, const float* __restrict__ csr_w,
    const float* __restrict__ dinv,
    const float* __restrict__ hw, const float* __restrict__ hprev,
    const float* __restrict__ bias, const float* __restrict__ gamma,
    const float* __restrict__ beta, const float* __restrict__ mean,
    const float* __restrict__ var,
    float* __restrict__ hout, int with_res) {
    int node = (blockIdx.x * 256 + threadIdx.x) >> 6;
    if (node >= NN) return;
    int lane = threadIdx.x & 63;
    int d0 = lane * 2;
    int s = offs[node], e = ends[node];
    float a0 = 0.0f, a1 = 0.0f;
    int j = s;
    for (; j + 3 < e; j += 4) {  // 4-deep for load overlap
        int s0 = csr_src[j], s1 = csr_src[j + 1], s2 = csr_src[j + 2], s3 = csr_src[j + 3];
        float w0 = csr_w[j], w1 = csr_w[j + 1], w2 = csr_w[j + 2], w3 = csr_w[j + 3];
        float2 v0 = *(const float2*)(hw + (size_t)s0 * HID + d0);
        float2 v1 = *(const float2*)(hw + (size_t)s1 * HID + d0);
        float2 v2 = *(const float2*)(hw + (size_t)s2 * HID + d0);
        float2 v3 = *(const float2*)(hw + (size_t)s3 * HID + d0);
        a0 += w0 * v0.x + w1 * v1.x + w2 * v2.x + w3 * v3.x;
        a1 += w0 * v0.y + w1 * v1.y + w2 * v2.y + w3 * v3.y;
    }
    for (; j < e; ++j) {
        int s0 = csr_src[j];
        float w0 = csr_w[j];
        float2 v0 = *(const float2*)(hw + (size_t)s0 * HID + d0);
        a0 += w0 * v0.x;
        a1 += w0 * v0.y;
    }
    float di = dinv[node];
    float sw = di * di;
    float2 hv = *(const float2*)(hw + (size_t)node * HID + d0);
    a0 += sw * hv.x;
    a1 += sw * hv.y;
    // bias + BN + ReLU (+ residual)
    float o0 = a0 + bias[d0 + 0];
    float o1 = a1 + bias[d0 + 1];
    o0 = (o0 - mean[d0 + 0]) * rsqrtf(var[d0 + 0] + BN_EPS) * gamma[d0 + 0] + beta[d0 + 0];
    o1 = (o1 - mean[d0 + 1]) * rsqrtf(var[d0 + 1] + BN_EPS) * gamma[d0 + 1] + beta[d0 + 1];
    o0 = fmaxf(o0, 0.0f);
    o1 = fmaxf(o1, 0.0f);
    if (with_res) {
        float2 p = *(const float2*)(hprev + (size_t)node * HID + d0);
        o0 += p.x;
        o1 += p.y;
    }
    float2 o;
    o.x = o0; o.y = o1;
    *(float2*)(hout + (size_t)node * HID + d0) = o;
}

// ======================= pool (segmented, batch sorted, no atomics) =======================
__device__ __forceinline__ int lower_bound_dev(const int* __restrict__ a, int n, int v) {
    int lo = 0, hi = n;
    while (lo < hi) {
        int m = (lo + hi) >> 1;
        if (a[m] < v) lo = m + 1; else hi = m;
    }
    return lo;
}

// one block (256 thr) per graph: thread t owns feature t&127, half t>>7
__global__ __launch_bounds__(256) void k_pool_seg(const float* __restrict__ h,
                                                  const int* __restrict__ batch,
                                                  float* __restrict__ gfeat) {
    __shared__ int range[2];
    __shared__ float s[256];
    int g = blockIdx.x, t = threadIdx.x;
    if (t == 0) {
        range[0] = lower_bound_dev(batch, NN, g);
        range[1] = lower_bound_dev(batch, NN, g + 1);
    }
    __syncthreads();
    int start = range[0], end = range[1];
    int f = t & 127, half = t >> 7;
    float acc = 0.0f;
    for (int i = start + half; i < end; i += 2)
        acc += h[(size_t)i * HID + f];
    s[t] = acc;
    __syncthreads();
    if (t < 128) {
        float sum = s[t] + s[t + 128];
        float cnt = (float)(end - start);
        gfeat[(size_t)g * HID + t] = sum / fmaxf(cnt, 1.0f);
    }
}

// ======================= MLP =======================
__global__ void k_mlp0(const float* __restrict__ gfeat,
                       const float* __restrict__ W, const float* __restrict__ b,
                       float* __restrict__ out) {
    __shared__ float srow[HID];
    int g = blockIdx.x, t = threadIdx.x;  // 128 threads
    if (t < HID) srow[t] = gfeat[(size_t)g * HID + t];
    __syncthreads();
    for (int j = t; j < FFN; j += 128) {
        float acc = b[j];
        for (int k = 0; k < HID; ++k) acc += srow[k] * W[k * FFN + j];
        out[(size_t)g * FFN + j] = fmaxf(acc, 0.0f);
    }
}

__global__ void k_mlp1(const float* __restrict__ in, const float* __restrict__ W,
                       const float* __restrict__ b, float* __restrict__ out) {
    __shared__ float srow[FFN];
    int g = blockIdx.x, t = threadIdx.x;  // 128 threads
    for (int k = t; k < FFN; k += 128) srow[k] = in[(size_t)g * FFN + k];
    __syncthreads();
    for (int j = t; j < FFN; j += 128) {
        float acc = b[j];
        for (int k = 0; k < FFN; ++k) acc += srow[k] * W[k * FFN + j];
        out[(size_t)g * FFN + j] = fmaxf(acc, 0.0f);
    }
}

__global__ void k_mlp2(const float* __restrict__ in, const float* __restrict__ W,
                       const float* __restrict__ b, float* __restrict__ out) {
    int g = blockIdx.x, lane = threadIdx.x;  // 64 threads
    float acc = 0.0f;
    for (int k = lane; k < FFN; k += 64) acc += in[(size_t)g * FFN + k] * W[k];
    for (int off = 32; off > 0; off >>= 1) acc += __shfl_down(acc, off);
    if (lane == 0) out[g] = acc + b[0];
}

extern "C" void kernel_launch(void* const* d_in, const int* in_sizes, int n_in,
                              void* d_out, int out_size, void* d_ws, size_t ws_size,
                              hipStream_t stream) {
    const float* x    = (const float*)d_in[0];
    const int*   ei   = (const int*)d_in[1];    // [2,E]: rows then cols
    const int*   batch= (const int*)d_in[2];
    const float* encW = (const float*)d_in[3];
    const float* encb = (const float*)d_in[4];
    const float* Ws   = (const float*)d_in[5];
    const float* bs   = (const float*)d_in[6];
    const float* gam  = (const float*)d_in[7];
    const float* bet  = (const float*)d_in[8];
    const float* mean = (const float*)d_in[9];
    const float* var  = (const float*)d_in[10];
    const float* W0   = (const float*)d_in[11];
    const float* b0   = (const float*)d_in[12];
    const float* W1   = (const float*)d_in[13];
    const float* b1   = (const float*)d_in[14];
    const float* W2   = (const float*)d_in[15];
    const float* b2   = (const float*)d_in[16];
    float* out = (float*)d_out;

    char* w = (char*)d_ws;
    float* dinv    = (float*)w; w += alignup((size_t)NN * 4);
    int*   counts  = (int*)w;   w += alignup((size_t)NN * 4);
    int*   incl    = (int*)w;   w += alignup((size_t)NN * 4);
    int*   bsums   = (int*)w;   w += alignup((size_t)NSCAN * 4);
    int*   offs    = (int*)w;   w += alignup((size_t)NN * 4);
    int*   cursor  = (int*)w;   w += alignup((size_t)NN * 4);
    int*   csr_src = (int*)w;   w += alignup((size_t)NE * 4);
    float* csr_w   = (float*)w; w += alignup((size_t)NE * 4);
    float* hA      = (float*)w; w += alignup((size_t)NN * HID * 4);
    float* hB      = (float*)w; w += alignup((size_t)NN * HID * 4);
    float* hw_     = (float*)w; w += alignup((size_t)NN * HID * 4);
    float* gfeat   = (float*)w; w += alignup((size_t)NG * HID * 4);
    float* m0      = (float*)w; w += alignup((size_t)NG * FFN * 4);
    float* m1      = (float*)w; w += alignup((size_t)NG * FFN * 4);

    const int* row = ei;
    const int* col = ei + NE;

    // ---- CSR build (per launch; deterministic work) ----
    k_count_init<<<(NN + 255) / 256, 256, 0, stream>>>(counts);
    k_count<<<(NE + 255) / 256, 256, 0, stream>>>(col, counts);
    k_dinv<<<(NN + 255) / 256, 256, 0, stream>>>(counts, dinv);
    k_scan1<<<NSCAN, 256, 0, stream>>>(counts, incl, bsums);
    k_scan2<<<1, 128, 0, stream>>>(bsums);
    k_scan3<<<(NN + 255) / 256, 256, 0, stream>>>(counts, incl, bsums, offs, cursor);
    k_fill<<<(NE + 255) / 256, 256, 0, stream>>>(row, col, dinv, cursor, csr_src, csr_w);

    // ---- encoder ----
    k_enc<<<(NN + 63) / 64, 256, 0, stream>>>(x, encW, encb, hA);

    float* hcur = hA;
    float* hnext = hB;
    for (int l = 0; l < NL; ++l) {
        k_gemm128<<<(NN + 63) / 64, 256, 0, stream>>>(hcur, Ws + (size_t)l * HID * HID, hw_);
        k_gather<<<(NN * 64 + 255) / 256, 256, 0, stream>>>(
            offs, cursor, csr_src, csr_w, dinv, hw_, hcur,
            bs + l * HID, gam + l * HID, bet + l * HID, mean + l * HID, var + l * HID,
            hnext, l > 0 ? 1 : 0);
        float* tmp = hcur; hcur = hnext; hnext = tmp;
    }

    // ---- pool + MLP ----
    k_pool_seg<<<NG, 256, 0, stream>>>(hcur, batch, gfeat);
    k_mlp0<<<NG, 128, 0, stream>>>(gfeat, W0, b0, m0);
    k_mlp1<<<NG, 128, 0, stream>>>(m0, W1, b1, m1);
    k_mlp2<<<NG, 64, 0, stream>>>(m1, W2, b2, out);
}

// Round 4
// 921.695 us; speedup vs baseline: 12.7707x; 1.2767x over previous
//
#include <hip/hip_runtime.h>
#include <hip/hip_fp16.h>

#define NN 100000
#define NE 1600000
#define FIN 64
#define HID 128
#define NL 4
#define NG 512
#define FFN 300
#define BN_EPS 1e-5f
#define SCAN_BLK 1024
#define NSCAN ((NN + SCAN_BLK - 1) / SCAN_BLK)   // 98

static inline size_t alignup(size_t x) { return (x + 255) & ~(size_t)255; }

struct half8 { __half2 h[4]; };   // 16 B

// ======================= CSR build =======================
__global__ void k_count_init(int* counts) {
    int i = blockIdx.x * 256 + threadIdx.x;
    if (i < NN) counts[i] = 0;
}

__global__ void k_count(const int* __restrict__ col, int* __restrict__ counts) {
    int e = blockIdx.x * 256 + threadIdx.x;
    if (e < NE) atomicAdd(&counts[col[e]], 1);
}

__global__ void k_dinv(const int* __restrict__ counts, float* __restrict__ dinv) {
    int i = blockIdx.x * 256 + threadIdx.x;
    if (i < NN) dinv[i] = rsqrtf((float)(counts[i] + 1));  // +1 self-loop
}

__global__ __launch_bounds__(256) void k_scan1(const int* __restrict__ counts,
                                               int* __restrict__ incl,
                                               int* __restrict__ bsums) {
    __shared__ int s[256];
    int t = threadIdx.x;
    int base = blockIdx.x * SCAN_BLK + t * 4;
    int c[4];
    #pragma unroll
    for (int j = 0; j < 4; ++j) c[j] = (base + j < NN) ? counts[base + j] : 0;
    int tsum = c[0] + c[1] + c[2] + c[3];
    s[t] = tsum;
    __syncthreads();
    for (int off = 1; off < 256; off <<= 1) {
        int v = (t >= off) ? s[t - off] : 0;
        __syncthreads();
        s[t] += v;
        __syncthreads();
    }
    if (t == 255) bsums[blockIdx.x] = s[255];
    int run = s[t] - tsum;  // exclusive across threads
    #pragma unroll
    for (int j = 0; j < 4; ++j) {
        run += c[j];
        if (base + j < NN) incl[base + j] = run;  // inclusive within block
    }
}

__global__ void k_scan2(int* bsums) {  // single block, 128 threads
    __shared__ int s[128];
    int t = threadIdx.x;
    int v = (t < NSCAN) ? bsums[t] : 0;
    s[t] = v;
    __syncthreads();
    for (int off = 1; off < 128; off <<= 1) {
        int u = (t >= off) ? s[t - off] : 0;
        __syncthreads();
        s[t] += u;
        __syncthreads();
    }
    if (t < NSCAN) bsums[t] = s[t] - v;  // exclusive block offsets
}

__global__ void k_scan3(const int* __restrict__ counts, const int* __restrict__ incl,
                        const int* __restrict__ bsums, int* __restrict__ offs,
                        int* __restrict__ cursor) {
    int i = blockIdx.x * 256 + threadIdx.x;
    if (i >= NN) return;
    int off = incl[i] - counts[i] + bsums[i / SCAN_BLK];
    offs[i] = off;
    cursor[i] = off;
}

__global__ void k_fill(const int* __restrict__ row, const int* __restrict__ col,
                       const float* __restrict__ dinv, int* __restrict__ cursor,
                       int* __restrict__ csr_src, float* __restrict__ csr_w) {
    int e = blockIdx.x * 256 + threadIdx.x;
    if (e >= NE) return;
    int r = row[e], c = col[e];
    int pos = atomicAdd(&cursor[c], 1);
    csr_src[pos] = r;
    csr_w[pos] = dinv[r] * dinv[c];
}

// ======================= encoder: x[N,64]@W -> h fp16 =======================
__global__ __launch_bounds__(256) void k_enc(const float* __restrict__ x,
                                             const float* __restrict__ W,
                                             const float* __restrict__ b,
                                             __half* __restrict__ h) {
    __shared__ float sW[FIN * HID];
    __shared__ float sx[64 * (FIN + 1)];
    int t = threadIdx.x;
    int row0 = blockIdx.x * 64;
    for (int i = t; i < FIN * HID; i += 256) sW[i] = W[i];
    for (int i = t; i < 64 * FIN; i += 256) {
        int r = i >> 6, k = i & 63;
        sx[r * (FIN + 1) + k] = (row0 + r < NN) ? x[(size_t)(row0 + r) * FIN + k] : 0.0f;
    }
    __syncthreads();
    int tx = t & 15, ty = t >> 4;
    int j0 = tx * 8, r0 = ty * 4;
    float acc[4][8];
    #pragma unroll
    for (int r = 0; r < 4; ++r)
        #pragma unroll
        for (int j = 0; j < 8; ++j) acc[r][j] = 0.0f;
    for (int k = 0; k < FIN; ++k) {
        float xv[4];
        #pragma unroll
        for (int r = 0; r < 4; ++r) xv[r] = sx[(r0 + r) * (FIN + 1) + k];
        float4 w0 = *(const float4*)&sW[k * HID + j0];
        float4 w1 = *(const float4*)&sW[k * HID + j0 + 4];
        float wv[8] = {w0.x, w0.y, w0.z, w0.w, w1.x, w1.y, w1.z, w1.w};
        #pragma unroll
        for (int r = 0; r < 4; ++r)
            #pragma unroll
            for (int j = 0; j < 8; ++j) acc[r][j] += xv[r] * wv[j];
    }
    #pragma unroll
    for (int r = 0; r < 4; ++r) {
        int rowi = row0 + r0 + r;
        if (rowi < NN) {
            half8 o;
            #pragma unroll
            for (int p = 0; p < 4; ++p)
                o.h[p] = __floats2half2_rn(acc[r][2 * p] + b[j0 + 2 * p],
                                           acc[r][2 * p + 1] + b[j0 + 2 * p + 1]);
            *(half8*)&h[(size_t)rowi * HID + j0] = o;
        }
    }
}

// ============ layer GEMM: h(fp16)[N,128] @ W(fp32) -> hw fp16 ============
__global__ __launch_bounds__(256) void k_gemm128(const __half* __restrict__ h,
                                                 const float* __restrict__ W,
                                                 __half* __restrict__ hw) {
    __shared__ float sW[64 * HID];
    __shared__ float sx[64 * (HID + 1)];
    int t = threadIdx.x;
    int row0 = blockIdx.x * 64;
    // load 64 rows x 128 halves; 4 halves (8 B) per iteration
    for (int i = t; i < 64 * 32; i += 256) {
        int r = i >> 5, c4 = (i & 31) * 4;
        float v0 = 0.0f, v1 = 0.0f, v2 = 0.0f, v3 = 0.0f;
        if (row0 + r < NN) {
            float2 raw = *(const float2*)(h + (size_t)(row0 + r) * HID + c4);
            const __half2* ph = (const __half2*)&raw;
            float2 a = __half22float2(ph[0]);
            float2 bb = __half22float2(ph[1]);
            v0 = a.x; v1 = a.y; v2 = bb.x; v3 = bb.y;
        }
        float* dst = &sx[r * (HID + 1) + c4];
        dst[0] = v0; dst[1] = v1; dst[2] = v2; dst[3] = v3;
    }
    int tx = t & 15, ty = t >> 4;
    int j0 = tx * 8, r0 = ty * 4;
    float acc[4][8];
    #pragma unroll
    for (int r = 0; r < 4; ++r)
        #pragma unroll
        for (int j = 0; j < 8; ++j) acc[r][j] = 0.0f;
    for (int kk = 0; kk < HID; kk += 64) {
        __syncthreads();
        for (int i = t; i < 64 * HID; i += 256) sW[i] = W[kk * HID + i];
        __syncthreads();
        for (int k = 0; k < 64; ++k) {
            float xv[4];
            #pragma unroll
            for (int r = 0; r < 4; ++r) xv[r] = sx[(r0 + r) * (HID + 1) + kk + k];
            float4 w0 = *(const float4*)&sW[k * HID + j0];
            float4 w1 = *(const float4*)&sW[k * HID + j0 + 4];
            float wv[8] = {w0.x, w0.y, w0.z, w0.w, w1.x, w1.y, w1.z, w1.w};
            #pragma unroll
            for (int r = 0; r < 4; ++r)
                #pragma unroll
                for (int j = 0; j < 8; ++j) acc[r][j] += xv[r] * wv[j];
        }
    }
    #pragma unroll
    for (int r = 0; r < 4; ++r) {
        int rowi = row0 + r0 + r;
        if (rowi < NN) {
            half8 o;
            #pragma unroll
            for (int p = 0; p < 4; ++p)
                o.h[p] = __floats2half2_rn(acc[r][2 * p], acc[r][2 * p + 1]);
            *(half8*)&hw[(size_t)rowi * HID + j0] = o;
        }
    }
}

// ======= fused gather + self-loop + bias + BN + ReLU + residual (fp16 payload) =======
// one wave (64 lanes) per node; lane handles 2 features (__half2)
__global__ __launch_bounds__(256) void k_gather(
    const int* __restrict__ offs, const int* __restrict__ ends,
    const int* __restrict__ csr_src, const float* __restrict__ csr_w,
    const float* __restrict__ dinv,
    const __half* __restrict__ hw, const __half* __restrict__ hprev,
    const float* __restrict__ bias, const float* __restrict__ gamma,
    const float* __restrict__ beta, const float* __restrict__ mean,
    const float* __restrict__ var,
    __half* __restrict__ hout, int with_res) {
    int node = (blockIdx.x * 256 + threadIdx.x) >> 6;
    if (node >= NN) return;
    int lane = threadIdx.x & 63;
    int d0 = lane * 2;
    int s = offs[node], e = ends[node];
    float a0 = 0.0f, a1 = 0.0f;
    int j = s;
    for (; j + 3 < e; j += 4) {  // 4-deep for load overlap
        int s0 = csr_src[j], s1 = csr_src[j + 1], s2 = csr_src[j + 2], s3 = csr_src[j + 3];
        float w0 = csr_w[j], w1 = csr_w[j + 1], w2 = csr_w[j + 2], w3 = csr_w[j + 3];
        float2 v0 = __half22float2(*(const __half2*)(hw + (size_t)s0 * HID + d0));
        float2 v1 = __half22float2(*(const __half2*)(hw + (size_t)s1 * HID + d0));
        float2 v2 = __half22float2(*(const __half2*)(hw + (size_t)s2 * HID + d0));
        float2 v3 = __half22float2(*(const __half2*)(hw + (size_t)s3 * HID + d0));
        a0 += w0 * v0.x + w1 * v1.x + w2 * v2.x + w3 * v3.x;
        a1 += w0 * v0.y + w1 * v1.y + w2 * v2.y + w3 * v3.y;
    }
    for (; j < e; ++j) {
        int s0 = csr_src[j];
        float w0 = csr_w[j];
        float2 v0 = __half22float2(*(const __half2*)(hw + (size_t)s0 * HID + d0));
        a0 += w0 * v0.x;
        a1 += w0 * v0.y;
    }
    float di = dinv[node];
    float sw = di * di;
    float2 hv = __half22float2(*(const __half2*)(hw + (size_t)node * HID + d0));
    a0 += sw * hv.x;
    a1 += sw * hv.y;
    // bias + BN + ReLU (+ residual)
    float o0 = a0 + bias[d0 + 0];
    float o1 = a1 + bias[d0 + 1];
    o0 = (o0 - mean[d0 + 0]) * rsqrtf(var[d0 + 0] + BN_EPS) * gamma[d0 + 0] + beta[d0 + 0];
    o1 = (o1 - mean[d0 + 1]) * rsqrtf(var[d0 + 1] + BN_EPS) * gamma[d0 + 1] + beta[d0 + 1];
    o0 = fmaxf(o0, 0.0f);
    o1 = fmaxf(o1, 0.0f);
    if (with_res) {
        float2 p = __half22float2(*(const __half2*)(hprev + (size_t)node * HID + d0));
        o0 += p.x;
        o1 += p.y;
    }
    *(__half2*)(hout + (size_t)node * HID + d0) = __floats2half2_rn(o0, o1);
}

// ======================= pool (segmented, batch sorted, no atomics) =======================
__device__ __forceinline__ int lower_bound_dev(const int* __restrict__ a, int n, int v) {
    int lo = 0, hi = n;
    while (lo < hi) {
        int m = (lo + hi) >> 1;
        if (a[m] < v) lo = m + 1; else hi = m;
    }
    return lo;
}

// one block (256 thr) per graph: thread t owns feature t&127, half t>>7
__global__ __launch_bounds__(256) void k_pool_seg(const __half* __restrict__ h,
                                                  const int* __restrict__ batch,
                                                  float* __restrict__ gfeat) {
    __shared__ int range[2];
    __shared__ float s[256];
    int g = blockIdx.x, t = threadIdx.x;
    if (t == 0) {
        range[0] = lower_bound_dev(batch, NN, g);
        range[1] = lower_bound_dev(batch, NN, g + 1);
    }
    __syncthreads();
    int start = range[0], end = range[1];
    int f = t & 127, half = t >> 7;
    float acc = 0.0f;
    for (int i = start + half; i < end; i += 2)
        acc += __half2float(h[(size_t)i * HID + f]);
    s[t] = acc;
    __syncthreads();
    if (t < 128) {
        float sum = s[t] + s[t + 128];
        float cnt = (float)(end - start);
        gfeat[(size_t)g * HID + t] = sum / fmaxf(cnt, 1.0f);
    }
}

// ======================= MLP =======================
__global__ void k_mlp0(const float* __restrict__ gfeat,
                       const float* __restrict__ W, const float* __restrict__ b,
                       float* __restrict__ out) {
    __shared__ float srow[HID];
    int g = blockIdx.x, t = threadIdx.x;  // 128 threads
    if (t < HID) srow[t] = gfeat[(size_t)g * HID + t];
    __syncthreads();
    for (int j = t; j < FFN; j += 128) {
        float acc = b[j];
        for (int k = 0; k < HID; ++k) acc += srow[k] * W[k * FFN + j];
        out[(size_t)g * FFN + j] = fmaxf(acc, 0.0f);
    }
}

__global__ void k_mlp1(const float* __restrict__ in, const float* __restrict__ W,
                       const float* __restrict__ b, float* __restrict__ out) {
    __shared__ float srow[FFN];
    int g = blockIdx.x, t = threadIdx.x;  // 128 threads
    for (int k = t; k < FFN; k += 128) srow[k] = in[(size_t)g * FFN + k];
    __syncthreads();
    for (int j = t; j < FFN; j += 128) {
        float acc = b[j];
        for (int k = 0; k < FFN; ++k) acc += srow[k] * W[k * FFN + j];
        out[(size_t)g * FFN + j] = fmaxf(acc, 0.0f);
    }
}

__global__ void k_mlp2(const float* __restrict__ in, const float* __restrict__ W,
                       const float* __restrict__ b, float* __restrict__ out) {
    int g = blockIdx.x, lane = threadIdx.x;  // 64 threads
    float acc = 0.0f;
    for (int k = lane; k < FFN; k += 64) acc += in[(size_t)g * FFN + k] * W[k];
    for (int off = 32; off > 0; off >>= 1) acc += __shfl_down(acc, off);
    if (lane == 0) out[g] = acc + b[0];
}

extern "C" void kernel_launch(void* const* d_in, const int* in_sizes, int n_in,
                              void* d_out, int out_size, void* d_ws, size_t ws_size,
                              hipStream_t stream) {
    const float* x    = (const float*)d_in[0];
    const int*   ei   = (const int*)d_in[1];    // [2,E]: rows then cols
    const int*   batch= (const int*)d_in[2];
    const float* encW = (const float*)d_in[3];
    const float* encb = (const float*)d_in[4];
    const float* Ws   = (const float*)d_in[5];
    const float* bs   = (const float*)d_in[6];
    const float* gam  = (const float*)d_in[7];
    const float* bet  = (const float*)d_in[8];
    const float* mean = (const float*)d_in[9];
    const float* var  = (const float*)d_in[10];
    const float* W0   = (const float*)d_in[11];
    const float* b0   = (const float*)d_in[12];
    const float* W1   = (const float*)d_in[13];
    const float* b1   = (const float*)d_in[14];
    const float* W2   = (const float*)d_in[15];
    const float* b2   = (const float*)d_in[16];
    float* out = (float*)d_out;

    char* w = (char*)d_ws;
    float*  dinv    = (float*)w;  w += alignup((size_t)NN * 4);
    int*    counts  = (int*)w;    w += alignup((size_t)NN * 4);
    int*    incl    = (int*)w;    w += alignup((size_t)NN * 4);
    int*    bsums   = (int*)w;    w += alignup((size_t)NSCAN * 4);
    int*    offs    = (int*)w;    w += alignup((size_t)NN * 4);
    int*    cursor  = (int*)w;    w += alignup((size_t)NN * 4);
    int*    csr_src = (int*)w;    w += alignup((size_t)NE * 4);
    float*  csr_w   = (float*)w;  w += alignup((size_t)NE * 4);
    __half* hA      = (__half*)w; w += alignup((size_t)NN * HID * 2);
    __half* hB      = (__half*)w; w += alignup((size_t)NN * HID * 2);
    __half* hw_     = (__half*)w; w += alignup((size_t)NN * HID * 2);
    float*  gfeat   = (float*)w;  w += alignup((size_t)NG * HID * 4);
    float*  m0      = (float*)w;  w += alignup((size_t)NG * FFN * 4);
    float*  m1      = (float*)w;  w += alignup((size_t)NG * FFN * 4);

    const int* row = ei;
    const int* col = ei + NE;

    // ---- CSR build (per launch; deterministic work) ----
    k_count_init<<<(NN + 255) / 256, 256, 0, stream>>>(counts);
    k_count<<<(NE + 255) / 256, 256, 0, stream>>>(col, counts);
    k_dinv<<<(NN + 255) / 256, 256, 0, stream>>>(counts, dinv);
    k_scan1<<<NSCAN, 256, 0, stream>>>(counts, incl, bsums);
    k_scan2<<<1, 128, 0, stream>>>(bsums);
    k_scan3<<<(NN + 255) / 256, 256, 0, stream>>>(counts, incl, bsums, offs, cursor);
    k_fill<<<(NE + 255) / 256, 256, 0, stream>>>(row, col, dinv, cursor, csr_src, csr_w);

    // ---- encoder ----
    k_enc<<<(NN + 63) / 64, 256, 0, stream>>>(x, encW, encb, hA);

    __half* hcur = hA;
    __half* hnext = hB;
    for (int l = 0; l < NL; ++l) {
        k_gemm128<<<(NN + 63) / 64, 256, 0, stream>>>(hcur, Ws + (size_t)l * HID * HID, hw_);
        k_gather<<<(NN * 64 + 255) / 256, 256, 0, stream>>>(
            offs, cursor, csr_src, csr_w, dinv, hw_, hcur,
            bs + l * HID, gam + l * HID, bet + l * HID, mean + l * HID, var + l * HID,
            hnext, l > 0 ? 1 : 0);
        __half* tmp = hcur; hcur = hnext; hnext = tmp;
    }

    // ---- pool + MLP ----
    k_pool_seg<<<NG, 256, 0, stream>>>(hcur, batch, gfeat);
    k_mlp0<<<NG, 128, 0, stream>>>(gfeat, W0, b0, m0);
    k_mlp1<<<NG, 128, 0, stream>>>(m0, W1, b1, m1);
    k_mlp2<<<NG, 64, 0, stream>>>(m1, W2, b2, out);
}

// Round 5
// 899.160 us; speedup vs baseline: 13.0907x; 1.0251x over previous
//
#include <hip/hip_runtime.h>
#include <hip/hip_fp16.h>

#define NN 100000
#define NE 1600000
#define FIN 64
#define HID 128
#define NL 4
#define NG 512
#define FFN 300
#define BN_EPS 1e-5f
#define SCAN_BLK 1024
#define NSCAN ((NN + SCAN_BLK - 1) / SCAN_BLK)   // 98

static inline size_t alignup(size_t x) { return (x + 255) & ~(size_t)255; }

struct half8 { __half2 h[4]; };   // 16 B

// ======================= CSR build =======================
__global__ void k_count(const int* __restrict__ col, int* __restrict__ counts) {
    int e = blockIdx.x * 256 + threadIdx.x;
    if (e < NE) atomicAdd(&counts[col[e]], 1);
}

__global__ void k_dinv(const int* __restrict__ counts, float* __restrict__ dinv) {
    int i = blockIdx.x * 256 + threadIdx.x;
    if (i < NN) dinv[i] = rsqrtf((float)(counts[i] + 1));  // +1 self-loop
}

__global__ __launch_bounds__(256) void k_scan1(const int* __restrict__ counts,
                                               int* __restrict__ incl,
                                               int* __restrict__ bsums) {
    __shared__ int s[256];
    int t = threadIdx.x;
    int base = blockIdx.x * SCAN_BLK + t * 4;
    int c[4];
    #pragma unroll
    for (int j = 0; j < 4; ++j) c[j] = (base + j < NN) ? counts[base + j] : 0;
    int tsum = c[0] + c[1] + c[2] + c[3];
    s[t] = tsum;
    __syncthreads();
    for (int off = 1; off < 256; off <<= 1) {
        int v = (t >= off) ? s[t - off] : 0;
        __syncthreads();
        s[t] += v;
        __syncthreads();
    }
    if (t == 255) bsums[blockIdx.x] = s[255];
    int run = s[t] - tsum;  // exclusive across threads
    #pragma unroll
    for (int j = 0; j < 4; ++j) {
        run += c[j];
        if (base + j < NN) incl[base + j] = run;  // inclusive within block
    }
}

__global__ void k_scan2(int* bsums) {  // single block, 128 threads
    __shared__ int s[128];
    int t = threadIdx.x;
    int v = (t < NSCAN) ? bsums[t] : 0;
    s[t] = v;
    __syncthreads();
    for (int off = 1; off < 128; off <<= 1) {
        int u = (t >= off) ? s[t - off] : 0;
        __syncthreads();
        s[t] += u;
        __syncthreads();
    }
    if (t < NSCAN) bsums[t] = s[t] - v;  // exclusive block offsets
}

__global__ void k_scan3(const int* __restrict__ counts, const int* __restrict__ incl,
                        const int* __restrict__ bsums, int* __restrict__ offs,
                        int* __restrict__ cursor) {
    int i = blockIdx.x * 256 + threadIdx.x;
    if (i >= NN) return;
    int off = incl[i] - counts[i] + bsums[i / SCAN_BLK];
    offs[i] = off;
    cursor[i] = off;
}

__global__ void k_fill(const int* __restrict__ row, const int* __restrict__ col,
                       int* __restrict__ cursor, int* __restrict__ csr_src) {
    int e = blockIdx.x * 256 + threadIdx.x;
    if (e >= NE) return;
    int r = row[e], c = col[e];
    int pos = atomicAdd(&cursor[c], 1);
    csr_src[pos] = r;
}

// ======================= encoder: x[N,64]@W -> h fp16 =======================
__global__ __launch_bounds__(256) void k_enc(const float* __restrict__ x,
                                             const float* __restrict__ W,
                                             const float* __restrict__ b,
                                             __half* __restrict__ h) {
    __shared__ float sW[FIN * HID];
    __shared__ float sx[64 * (FIN + 1)];
    int t = threadIdx.x;
    int row0 = blockIdx.x * 64;
    for (int i = t; i < FIN * HID; i += 256) sW[i] = W[i];
    for (int i = t; i < 64 * FIN; i += 256) {
        int r = i >> 6, k = i & 63;
        sx[r * (FIN + 1) + k] = (row0 + r < NN) ? x[(size_t)(row0 + r) * FIN + k] : 0.0f;
    }
    __syncthreads();
    int tx = t & 15, ty = t >> 4;
    int j0 = tx * 8, r0 = ty * 4;
    float acc[4][8];
    #pragma unroll
    for (int r = 0; r < 4; ++r)
        #pragma unroll
        for (int j = 0; j < 8; ++j) acc[r][j] = 0.0f;
    for (int k = 0; k < FIN; ++k) {
        float xv[4];
        #pragma unroll
        for (int r = 0; r < 4; ++r) xv[r] = sx[(r0 + r) * (FIN + 1) + k];
        float4 w0 = *(const float4*)&sW[k * HID + j0];
        float4 w1 = *(const float4*)&sW[k * HID + j0 + 4];
        float wv[8] = {w0.x, w0.y, w0.z, w0.w, w1.x, w1.y, w1.z, w1.w};
        #pragma unroll
        for (int r = 0; r < 4; ++r)
            #pragma unroll
            for (int j = 0; j < 8; ++j) acc[r][j] += xv[r] * wv[j];
    }
    #pragma unroll
    for (int r = 0; r < 4; ++r) {
        int rowi = row0 + r0 + r;
        if (rowi < NN) {
            half8 o;
            #pragma unroll
            for (int p = 0; p < 4; ++p)
                o.h[p] = __floats2half2_rn(acc[r][2 * p] + b[j0 + 2 * p],
                                           acc[r][2 * p + 1] + b[j0 + 2 * p + 1]);
            *(half8*)&h[(size_t)rowi * HID + j0] = o;
        }
    }
}

// ==== layer GEMM: hw_scaled = dinv[row] * (h(fp16)[N,128] @ W(fp32)) -> fp16 ====
__global__ __launch_bounds__(256) void k_gemm128(const __half* __restrict__ h,
                                                 const float* __restrict__ W,
                                                 const float* __restrict__ dinv,
                                                 __half* __restrict__ hw) {
    __shared__ float sW[64 * HID];
    __shared__ float sx[64 * (HID + 1)];
    int t = threadIdx.x;
    int row0 = blockIdx.x * 64;
    // load 64 rows x 128 halves; 4 halves (8 B) per iteration
    for (int i = t; i < 64 * 32; i += 256) {
        int r = i >> 5, c4 = (i & 31) * 4;
        float v0 = 0.0f, v1 = 0.0f, v2 = 0.0f, v3 = 0.0f;
        if (row0 + r < NN) {
            float2 raw = *(const float2*)(h + (size_t)(row0 + r) * HID + c4);
            const __half2* ph = (const __half2*)&raw;
            float2 a = __half22float2(ph[0]);
            float2 bb = __half22float2(ph[1]);
            v0 = a.x; v1 = a.y; v2 = bb.x; v3 = bb.y;
        }
        float* dst = &sx[r * (HID + 1) + c4];
        dst[0] = v0; dst[1] = v1; dst[2] = v2; dst[3] = v3;
    }
    int tx = t & 15, ty = t >> 4;
    int j0 = tx * 8, r0 = ty * 4;
    float acc[4][8];
    #pragma unroll
    for (int r = 0; r < 4; ++r)
        #pragma unroll
        for (int j = 0; j < 8; ++j) acc[r][j] = 0.0f;
    for (int kk = 0; kk < HID; kk += 64) {
        __syncthreads();
        for (int i = t; i < 64 * HID; i += 256) sW[i] = W[kk * HID + i];
        __syncthreads();
        for (int k = 0; k < 64; ++k) {
            float xv[4];
            #pragma unroll
            for (int r = 0; r < 4; ++r) xv[r] = sx[(r0 + r) * (HID + 1) + kk + k];
            float4 w0 = *(const float4*)&sW[k * HID + j0];
            float4 w1 = *(const float4*)&sW[k * HID + j0 + 4];
            float wv[8] = {w0.x, w0.y, w0.z, w0.w, w1.x, w1.y, w1.z, w1.w};
            #pragma unroll
            for (int r = 0; r < 4; ++r)
                #pragma unroll
                for (int j = 0; j < 8; ++j) acc[r][j] += xv[r] * wv[j];
        }
    }
    #pragma unroll
    for (int r = 0; r < 4; ++r) {
        int rowi = row0 + r0 + r;
        if (rowi < NN) {
            float dv = dinv[rowi];
            half8 o;
            #pragma unroll
            for (int p = 0; p < 4; ++p)
                o.h[p] = __floats2half2_rn(dv * acc[r][2 * p], dv * acc[r][2 * p + 1]);
            *(half8*)&hw[(size_t)rowi * HID + j0] = o;
        }
    }
}

// == fused gather + self-loop + bias + BN + ReLU + residual (pre-scaled fp16 rows) ==
// h_agg[c] = dinv[c] * (sum_{r in N(c)} hw[r] + hw[c]);  one wave per node
__global__ __launch_bounds__(256) void k_gather(
    const int* __restrict__ offs, const int* __restrict__ ends,
    const int* __restrict__ csr_src,
    const float* __restrict__ dinv,
    const __half* __restrict__ hw, const __half* __restrict__ hprev,
    const float* __restrict__ bias, const float* __restrict__ gamma,
    const float* __restrict__ beta, const float* __restrict__ mean,
    const float* __restrict__ var,
    __half* __restrict__ hout, int with_res) {
    int node = (blockIdx.x * 256 + threadIdx.x) >> 6;
    if (node >= NN) return;
    int lane = threadIdx.x & 63;
    int d0 = lane * 2;
    int s = offs[node], e = ends[node];
    float a0 = 0.0f, a1 = 0.0f;
    int j = s;
    for (; j + 3 < e; j += 4) {  // 4-deep for load overlap
        int s0 = csr_src[j], s1 = csr_src[j + 1], s2 = csr_src[j + 2], s3 = csr_src[j + 3];
        float2 v0 = __half22float2(*(const __half2*)(hw + (size_t)s0 * HID + d0));
        float2 v1 = __half22float2(*(const __half2*)(hw + (size_t)s1 * HID + d0));
        float2 v2 = __half22float2(*(const __half2*)(hw + (size_t)s2 * HID + d0));
        float2 v3 = __half22float2(*(const __half2*)(hw + (size_t)s3 * HID + d0));
        a0 += v0.x + v1.x + v2.x + v3.x;
        a1 += v0.y + v1.y + v2.y + v3.y;
    }
    for (; j < e; ++j) {
        int s0 = csr_src[j];
        float2 v0 = __half22float2(*(const __half2*)(hw + (size_t)s0 * HID + d0));
        a0 += v0.x;
        a1 += v0.y;
    }
    // self-loop (pre-scaled row) then final dinv[c] scale
    float2 hv = __half22float2(*(const __half2*)(hw + (size_t)node * HID + d0));
    float dc = dinv[node];
    a0 = dc * (a0 + hv.x);
    a1 = dc * (a1 + hv.y);
    // bias + BN + ReLU (+ residual)
    float o0 = a0 + bias[d0 + 0];
    float o1 = a1 + bias[d0 + 1];
    o0 = (o0 - mean[d0 + 0]) * rsqrtf(var[d0 + 0] + BN_EPS) * gamma[d0 + 0] + beta[d0 + 0];
    o1 = (o1 - mean[d0 + 1]) * rsqrtf(var[d0 + 1] + BN_EPS) * gamma[d0 + 1] + beta[d0 + 1];
    o0 = fmaxf(o0, 0.0f);
    o1 = fmaxf(o1, 0.0f);
    if (with_res) {
        float2 p = __half22float2(*(const __half2*)(hprev + (size_t)node * HID + d0));
        o0 += p.x;
        o1 += p.y;
    }
    *(__half2*)(hout + (size_t)node * HID + d0) = __floats2half2_rn(o0, o1);
}

// ======================= pool (segmented, batch sorted, no atomics) =======================
__device__ __forceinline__ int lower_bound_dev(const int* __restrict__ a, int n, int v) {
    int lo = 0, hi = n;
    while (lo < hi) {
        int m = (lo + hi) >> 1;
        if (a[m] < v) lo = m + 1; else hi = m;
    }
    return lo;
}

// one block (256 thr) per graph: thread t owns feature t&127, half t>>7
__global__ __launch_bounds__(256) void k_pool_seg(const __half* __restrict__ h,
                                                  const int* __restrict__ batch,
                                                  float* __restrict__ gfeat) {
    __shared__ int range[2];
    __shared__ float s[256];
    int g = blockIdx.x, t = threadIdx.x;
    if (t == 0) {
        range[0] = lower_bound_dev(batch, NN, g);
        range[1] = lower_bound_dev(batch, NN, g + 1);
    }
    __syncthreads();
    int start = range[0], end = range[1];
    int f = t & 127, half = t >> 7;
    float acc = 0.0f;
    for (int i = start + half; i < end; i += 2)
        acc += __half2float(h[(size_t)i * HID + f]);
    s[t] = acc;
    __syncthreads();
    if (t < 128) {
        float sum = s[t] + s[t + 128];
        float cnt = (float)(end - start);
        gfeat[(size_t)g * HID + t] = sum / fmaxf(cnt, 1.0f);
    }
}

// ======================= MLP =======================
__global__ void k_mlp0(const float* __restrict__ gfeat,
                       const float* __restrict__ W, const float* __restrict__ b,
                       float* __restrict__ out) {
    __shared__ float srow[HID];
    int g = blockIdx.x, t = threadIdx.x;  // 128 threads
    if (t < HID) srow[t] = gfeat[(size_t)g * HID + t];
    __syncthreads();
    for (int j = t; j < FFN; j += 128) {
        float acc = b[j];
        for (int k = 0; k < HID; ++k) acc += srow[k] * W[k * FFN + j];
        out[(size_t)g * FFN + j] = fmaxf(acc, 0.0f);
    }
}

__global__ void k_mlp1(const float* __restrict__ in, const float* __restrict__ W,
                       const float* __restrict__ b, float* __restrict__ out) {
    __shared__ float srow[FFN];
    int g = blockIdx.x, t = threadIdx.x;  // 128 threads
    for (int k = t; k < FFN; k += 128) srow[k] = in[(size_t)g * FFN + k];
    __syncthreads();
    for (int j = t; j < FFN; j += 128) {
        float acc = b[j];
        for (int k = 0; k < FFN; ++k) acc += srow[k] * W[k * FFN + j];
        out[(size_t)g * FFN + j] = fmaxf(acc, 0.0f);
    }
}

__global__ void k_mlp2(const float* __restrict__ in, const float* __restrict__ W,
                       const float* __restrict__ b, float* __restrict__ out) {
    int g = blockIdx.x, lane = threadIdx.x;  // 64 threads
    float acc = 0.0f;
    for (int k = lane; k < FFN; k += 64) acc += in[(size_t)g * FFN + k] * W[k];
    for (int off = 32; off > 0; off >>= 1) acc += __shfl_down(acc, off);
    if (lane == 0) out[g] = acc + b[0];
}

extern "C" void kernel_launch(void* const* d_in, const int* in_sizes, int n_in,
                              void* d_out, int out_size, void* d_ws, size_t ws_size,
                              hipStream_t stream) {
    const float* x    = (const float*)d_in[0];
    const int*   ei   = (const int*)d_in[1];    // [2,E]: rows then cols
    const int*   batch= (const int*)d_in[2];
    const float* encW = (const float*)d_in[3];
    const float* encb = (const float*)d_in[4];
    const float* Ws   = (const float*)d_in[5];
    const float* bs   = (const float*)d_in[6];
    const float* gam  = (const float*)d_in[7];
    const float* bet  = (const float*)d_in[8];
    const float* mean = (const float*)d_in[9];
    const float* var  = (const float*)d_in[10];
    const float* W0   = (const float*)d_in[11];
    const float* b0   = (const float*)d_in[12];
    const float* W1   = (const float*)d_in[13];
    const float* b1   = (const float*)d_in[14];
    const float* W2   = (const float*)d_in[15];
    const float* b2   = (const float*)d_in[16];
    float* out = (float*)d_out;

    char* w = (char*)d_ws;
    float*  dinv    = (float*)w;  w += alignup((size_t)NN * 4);
    int*    counts  = (int*)w;    w += alignup((size_t)NN * 4);
    int*    incl    = (int*)w;    w += alignup((size_t)NN * 4);
    int*    bsums   = (int*)w;    w += alignup((size_t)NSCAN * 4);
    int*    offs    = (int*)w;    w += alignup((size_t)NN * 4);
    int*    cursor  = (int*)w;    w += alignup((size_t)NN * 4);
    int*    csr_src = (int*)w;    w += alignup((size_t)NE * 4);
    __half* hA      = (__half*)w; w += alignup((size_t)NN * HID * 2);
    __half* hB      = (__half*)w; w += alignup((size_t)NN * HID * 2);
    __half* hw_     = (__half*)w; w += alignup((size_t)NN * HID * 2);
    float*  gfeat   = (float*)w;  w += alignup((size_t)NG * HID * 4);
    float*  m0      = (float*)w;  w += alignup((size_t)NG * FFN * 4);
    float*  m1      = (float*)w;  w += alignup((size_t)NG * FFN * 4);

    const int* row = ei;
    const int* col = ei + NE;

    // ---- CSR build (per launch; deterministic work) ----
    hipMemsetAsync(counts, 0, (size_t)NN * 4, stream);
    k_count<<<(NE + 255) / 256, 256, 0, stream>>>(col, counts);
    k_dinv<<<(NN + 255) / 256, 256, 0, stream>>>(counts, dinv);
    k_scan1<<<NSCAN, 256, 0, stream>>>(counts, incl, bsums);
    k_scan2<<<1, 128, 0, stream>>>(bsums);
    k_scan3<<<(NN + 255) / 256, 256, 0, stream>>>(counts, incl, bsums, offs, cursor);
    k_fill<<<(NE + 255) / 256, 256, 0, stream>>>(row, col, cursor, csr_src);

    // ---- encoder ----
    k_enc<<<(NN + 63) / 64, 256, 0, stream>>>(x, encW, encb, hA);

    __half* hcur = hA;
    __half* hnext = hB;
    for (int l = 0; l < NL; ++l) {
        k_gemm128<<<(NN + 63) / 64, 256, 0, stream>>>(hcur, Ws + (size_t)l * HID * HID, dinv, hw_);
        k_gather<<<(NN * 64 + 255) / 256, 256, 0, stream>>>(
            offs, cursor, csr_src, dinv, hw_, hcur,
            bs + l * HID, gam + l * HID, bet + l * HID, mean + l * HID, var + l * HID,
            hnext, l > 0 ? 1 : 0);
        __half* tmp = hcur; hcur = hnext; hnext = tmp;
    }

    // ---- pool + MLP ----
    k_pool_seg<<<NG, 256, 0, stream>>>(hcur, batch, gfeat);
    k_mlp0<<<NG, 128, 0, stream>>>(gfeat, W0, b0, m0);
    k_mlp1<<<NG, 128, 0, stream>>>(m0, W1, b1, m1);
    k_mlp2<<<NG, 64, 0, stream>>>(m1, W2, b2, out);
}